// Round 9
// baseline (182.864 us; speedup 1.0000x reference)
//
#include <hip/hip_runtime.h>
#include <hip/hip_bf16.h>
#include <hip/hip_fp8.h>
#include <math.h>

typedef float floatx4 __attribute__((ext_vector_type(4)));
typedef long long i64;
typedef long long i64x2 __attribute__((ext_vector_type(2)));

#define N_ROWS 4096
#define DIM 512
#define LAM 0.5f
#define NTILE 128         // 64-row tiles per dim (8192/64)
#define TILE_BYTES 32768  // 64 rows * 512 B (fp8)

__device__ __forceinline__ unsigned int pack4_fp8(float a, float b, float c, float d) {
    unsigned int u0 = __hip_cvt_float_to_fp8(a, __HIP_SATFINITE, __HIP_E4M3);
    unsigned int u1 = __hip_cvt_float_to_fp8(b, __HIP_SATFINITE, __HIP_E4M3);
    unsigned int u2 = __hip_cvt_float_to_fp8(c, __HIP_SATFINITE, __HIP_E4M3);
    unsigned int u3 = __hip_cvt_float_to_fp8(d, __HIP_SATFINITE, __HIP_E4M3);
    return u0 | (u1 << 8) | (u2 << 16) | (u3 << 24);
}

// Z stored FRAGMENT-MAJOR fp8: tile t (64 rows), kc64 (k-chunk of 64),
// frag-row-group f (rows f*16..+15):
//   byte(t, kc64, f, lane, h, b) = t*32768 + kc64*4096 + f*1024 + lane*16 + h*8 + b
// holding Z[t*64 + f*16 + (lane&15)][kc64*64 + h*32 + (lane>>4)*8 + b].
// One global_load_dwordx4 at (t, kc64, f) + lane*16 IS the MFMA operand pair
// for k-halves h=0/1 — 64 lanes cover a contiguous 1 KB: perfectly coalesced,
// zero LDS in the GEMM loop.  (A- and B-operand layouts coincide for 16x16x32.)
//
// normalize: one 256-thr block per 16-row group (512 groups). Each wave
// normalizes 4 rows, scatters fp8 into an 8 KB LDS image, then the block
// copies out 8 contiguous 1 KB segments (coalesced both sides).
__global__ __launch_bounds__(256) void normalize_kernel(
    const float* __restrict__ ei, const float* __restrict__ ej,
    unsigned char* __restrict__ Zt, float* __restrict__ out) {
    if (blockIdx.x == 0 && threadIdx.x == 0) out[0] = 0.0f;
    const int g = blockIdx.x;                 // group [0, 512)
    const int tile = g >> 2, f = g & 3;
    const int t = threadIdx.x, w = t >> 6, lane = t & 63;
    __shared__ __align__(16) unsigned char img[8192];

    #pragma unroll
    for (int rr = 0; rr < 4; ++rr) {
        const int m16 = w * 4 + rr;           // row within group (waves disjoint)
        const int row = tile * 64 + f * 16 + m16;
        const float* __restrict__ src = (row < N_ROWS)
            ? (ei + (size_t)row * DIM)
            : (ej + (size_t)(row - N_ROWS) * DIM);
        const float4* s4 = (const float4*)src;
        float4 v0 = s4[lane];                 // k = 4*lane .. +3
        float4 v1 = s4[lane + 64];            // k = 256 + 4*lane .. +3
        float s = v0.x*v0.x + v0.y*v0.y + v0.z*v0.z + v0.w*v0.w
                + v1.x*v1.x + v1.y*v1.y + v1.z*v1.z + v1.w*v1.w;
        #pragma unroll
        for (int off = 32; off; off >>= 1) s += __shfl_xor(s, off);
        const float rn = rsqrtf(s);
        // laddr(k) = (k>>6)*1024 + (((k>>3)&3)*16 + m16)*16 + ((k>>5)&1)*8 + (k&7)
        const int k0 = 4 * lane;
        const int la0 = ((k0 >> 6) << 10) + (((((k0 >> 3) & 3) << 4) + m16) << 4)
                      + (((k0 >> 5) & 1) << 3) + (k0 & 7);
        *(unsigned int*)(img + la0) = pack4_fp8(v0.x*rn, v0.y*rn, v0.z*rn, v0.w*rn);
        const int k1 = 256 + 4 * lane;
        const int la1 = ((k1 >> 6) << 10) + (((((k1 >> 3) & 3) << 4) + m16) << 4)
                      + (((k1 >> 5) & 1) << 3) + (k1 & 7);
        *(unsigned int*)(img + la1) = pack4_fp8(v1.x*rn, v1.y*rn, v1.z*rn, v1.w*rn);
    }
    __syncthreads();
    // copy-out: thread t moves 32 B; dst segment kc64 = t>>5, offset (t*32)&1023
    const unsigned char* sp = img + t * 32;
    unsigned char* dp = Zt + (size_t)tile * TILE_BYTES + ((t >> 5) << 12)
                      + (f << 10) + ((t * 32) & 1023);
    *(i64x2*)dp        = *(const i64x2*)sp;
    *(i64x2*)(dp + 16) = *(const i64x2*)(sp + 16);
}

// Fused S = Z.Z^T (fp8 16x16x32 MFMA) + loss.  One wave per block, one 64x64
// tile per wave.  NO LDS: fragments load straight into VGPRs (coalesced 1 KB
// per instruction, fragment-major Z).  3-stage register ring, prefetch depth
// 2: hiding capacity ~= 2 waves/SIMD x 2 iters x 155 cyc >= 600 cyc, vs
// R1-R8's <200 (the 120 us plateau = unhidden ~1 us load latency; every prior
// round only changed HOW we wait, not how much we can hide).
// Triangular grid; tn>tm weighted x2; positives on tn==tm+64 local diagonals.
__global__ __launch_bounds__(64) void simloss_kernel(
    const unsigned char* __restrict__ Zt, float* __restrict__ out) {
    // --- triangular decode, NTILE = 128 ---
    const int id = blockIdx.x;
    int tm = (int)((2*NTILE + 1 - sqrtf((float)((2*NTILE+1)*(2*NTILE+1)) - 8.0f * (float)id)) * 0.5f);
    if (tm < 0) tm = 0; if (tm > NTILE-1) tm = NTILE-1;
    while ((tm + 1) * NTILE - ((tm + 1) * tm) / 2 <= id) ++tm;
    while (tm * NTILE - (tm * (tm - 1)) / 2 > id) --tm;
    const int tn = tm + (id - (tm * NTILE - (tm * (tm - 1)) / 2));

    const int lane = threadIdx.x;
    const int q = lane >> 4, m16 = lane & 15;

    const unsigned char* pA = Zt + (size_t)tm * TILE_BYTES + lane * 16;
    const unsigned char* pB = Zt + (size_t)tn * TILE_BYTES + lane * 16;

    i64x2 a[3][4], b[3][4];                   // 3-stage ring (fully unrolled)
    #pragma unroll
    for (int st = 0; st < 2; ++st)
        #pragma unroll
        for (int f = 0; f < 4; ++f) {
            a[st][f] = *(const i64x2*)(pA + st * 4096 + f * 1024);
            b[st][f] = *(const i64x2*)(pB + st * 4096 + f * 1024);
        }

    floatx4 acc[4][4] = {};

    #pragma unroll
    for (int kc = 0; kc < 8; ++kc) {
        const int cur = kc % 3;
        if (kc < 6) {
            const int nxt = (kc + 2) % 3, ko = (kc + 2) * 4096;
            #pragma unroll
            for (int f = 0; f < 4; ++f) {
                a[nxt][f] = *(const i64x2*)(pA + ko + f * 1024);
                b[nxt][f] = *(const i64x2*)(pB + ko + f * 1024);
            }
        }
        #pragma unroll
        for (int i = 0; i < 4; ++i)
            #pragma unroll
            for (int j = 0; j < 4; ++j) {
                acc[i][j] = __builtin_amdgcn_mfma_f32_16x16x32_fp8_fp8(a[cur][i].x, b[cur][j].x, acc[i][j], 0, 0, 0);
                acc[i][j] = __builtin_amdgcn_mfma_f32_16x16x32_fp8_fp8(a[cur][i].y, b[cur][j].y, acc[i][j], 0, 0, 0);
            }
    }

    // --- epilogue: C/D map row = i*16 + q*4 + rr, col = j*16 + m16 (tile-local) ---
    const int rowBase = tm * 64 + q * 4;
    const int colBase = tn * 64 + m16;
    float negsum = 0.0f, possum = 0.0f;
    #pragma unroll
    for (int j = 0; j < 4; ++j) {
        const int cg = colBase + j * 16;
        float p = 1.0f;
        #pragma unroll
        for (int i = 0; i < 4; ++i) {
            const int rg0 = rowBase + i * 16;
            #pragma unroll
            for (int rr = 0; rr < 4; ++rr) {
                const float sv = acc[i][j][rr];
                float e = __expf(sv - LAM);
                if (rg0 + rr == cg) e = 0.0f;         // mask main diagonal
                p *= (1.0f + e);
                if (cg == rg0 + rr + N_ROWS)          // positive pair (k, k+N)
                    possum += log1pf(expf(-sv + LAM));
            }
        }
        negsum += __logf(p);
    }
    if (tn != tm) negsum *= 2.0f;                     // symmetric tile (tn, tm)

    #pragma unroll
    for (int off = 32; off; off >>= 1) {
        negsum += __shfl_xor(negsum, off);
        possum += __shfl_xor(possum, off);
    }
    if (lane == 0)
        atomicAdd(out, negsum * (1.0f / (12.0f * (float)N_ROWS))
                     + possum * (1.0f / (float)N_ROWS));
}

extern "C" void kernel_launch(void* const* d_in, const int* in_sizes, int n_in,
                              void* d_out, int out_size, void* d_ws, size_t ws_size,
                              hipStream_t stream) {
    const float* ei = (const float*)d_in[0];
    const float* ej = (const float*)d_in[1];
    float* out = (float*)d_out;
    unsigned char* Zt = (unsigned char*)d_ws;  // fragment-major fp8 Z: 4 MB

    normalize_kernel<<<512, 256, 0, stream>>>(ei, ej, Zt, out);
    simloss_kernel<<<NTILE * (NTILE + 1) / 2, 64, 0, stream>>>(Zt, out);
}